// Round 1
// baseline (125.308 us; speedup 1.0000x reference)
//
#include <hip/hip_runtime.h>

#define NLVL 16
#define NPTS_PER_BLOCK 256

// Per-level constants derived from the reference's _level_params() (float64 math,
// then cast to f32 exactly as numpy does).
__device__ __constant__ float  kScale[NLVL] = {
    15.0f, 19.15873679831797f, 24.39841683149119f, 31.0f,
    39.31747359663594f, 49.79683366298238f, 63.0f, 79.63494719327189f,
    100.59366732596477f, 127.0f, 160.26989438654376f, 202.18733465192954f,
    255.0f, 321.5397887730875f, 405.3746693038591f, 511.0f
};
__device__ __constant__ int kRes[NLVL] = {
    16, 21, 26, 32, 41, 51, 64, 81, 102, 128, 162, 204, 256, 323, 407, 512
};
__device__ __constant__ int kOff[NLVL] = {
    0, 4096, 13360, 30936, 63704, 132632, 265288, 527432,
    1051720, 1576008, 2100296, 2624584, 3148872, 3673160, 4197448, 4721736
};
// Levels 0..6: lin < res^3 <= hsize  -> modulo is a no-op.
// Levels 7..15: hsize == 2^19       -> lin & 0x7FFFF.

__global__ __launch_bounds__(NPTS_PER_BLOCK)
void hashgrid_mlp_kernel(const float* __restrict__ coords,   // [N,3]
                         const float* __restrict__ emb,      // [total,2]
                         const float* __restrict__ W0,       // [32,32]
                         const float* __restrict__ b0,       // [32]
                         const float* __restrict__ W1,       // [32,32]
                         const float* __restrict__ b1,       // [32]
                         const float* __restrict__ W2,       // [32,1]
                         const float* __restrict__ b2,       // [1]
                         float* __restrict__ out,            // [N]
                         int n)
{
    const int tid = blockIdx.x * blockDim.x + threadIdx.x;
    if (tid >= n) return;

    const float cx = coords[tid * 3 + 0];
    const float cy = coords[tid * 3 + 1];
    const float cz = coords[tid * 3 + 2];
    // x = (c + 1) / 2  (bound = 1)
    const float x = (cx + 1.0f) * 0.5f;
    const float y = (cy + 1.0f) * 0.5f;
    const float z = (cz + 1.0f) * 0.5f;

    const float2* __restrict__ tab = (const float2*)emb;

    float enc[2 * NLVL];

#pragma unroll
    for (int l = 0; l < NLVL; ++l) {
        const float s = kScale[l];
        const int   r = kRes[l];

        const float px = x * s, py = y * s, pz = z * s;
        const float fpx = floorf(px), fpy = floorf(py), fpz = floorf(pz);
        const float tx = px - fpx, ty = py - fpy, tz = pz - fpz;
        const int bx = (int)fpx, by = (int)fpy, bz = (int)fpz;

        const int lin0 = bx + r * by + r * r * bz;
        const int off = kOff[l];

        float a0 = 0.0f, a1 = 0.0f;
#pragma unroll
        for (int c = 0; c < 8; ++c) {
            const int ix = c & 1, iy = (c >> 1) & 1, iz = (c >> 2) & 1;
            int lin = lin0 + ix + r * iy + r * r * iz;
            if (l >= 7) lin &= 0x7FFFF;   // hsize == 2^19 for levels 7..15
            const int idx = off + lin;
            const float w = (ix ? tx : 1.0f - tx)
                          * (iy ? ty : 1.0f - ty)
                          * (iz ? tz : 1.0f - tz);
            const float2 f = tab[idx];
            a0 = fmaf(w, f.x, a0);
            a1 = fmaf(w, f.y, a1);
        }
        enc[2 * l + 0] = a0;
        enc[2 * l + 1] = a1;
    }

    // ---- MLP: 32 -> 32 (leaky 0.01) -> 32 (leaky 0.01) -> 1 ----
    // Weight indices are compile-time constants with uniform base pointers, so
    // the compiler emits s_load_dwordx16 into SGPRs (no per-lane traffic).
    float h0[32];
#pragma unroll
    for (int j = 0; j < 32; ++j) h0[j] = b0[j];
#pragma unroll
    for (int i = 0; i < 32; ++i) {
        const float e = enc[i];
#pragma unroll
        for (int j = 0; j < 32; ++j) h0[j] = fmaf(e, W0[i * 32 + j], h0[j]);
    }
#pragma unroll
    for (int j = 0; j < 32; ++j) h0[j] = (h0[j] >= 0.0f) ? h0[j] : 0.01f * h0[j];

    float h1[32];
#pragma unroll
    for (int j = 0; j < 32; ++j) h1[j] = b1[j];
#pragma unroll
    for (int i = 0; i < 32; ++i) {
        const float e = h0[i];
#pragma unroll
        for (int j = 0; j < 32; ++j) h1[j] = fmaf(e, W1[i * 32 + j], h1[j]);
    }
#pragma unroll
    for (int j = 0; j < 32; ++j) h1[j] = (h1[j] >= 0.0f) ? h1[j] : 0.01f * h1[j];

    float acc = b2[0];
#pragma unroll
    for (int j = 0; j < 32; ++j) acc = fmaf(h1[j], W2[j], acc);

    out[tid] = acc;
}

extern "C" void kernel_launch(void* const* d_in, const int* in_sizes, int n_in,
                              void* d_out, int out_size, void* d_ws, size_t ws_size,
                              hipStream_t stream) {
    const float* coords = (const float*)d_in[0];   // [N,1,3]
    const float* emb    = (const float*)d_in[1];   // [total,1,2]
    const float* W0     = (const float*)d_in[2];
    const float* b0     = (const float*)d_in[3];
    const float* W1     = (const float*)d_in[4];
    const float* b1     = (const float*)d_in[5];
    const float* W2     = (const float*)d_in[6];
    const float* b2     = (const float*)d_in[7];
    float* out = (float*)d_out;

    const int n = in_sizes[0] / 3;   // 262144
    const int blocks = (n + NPTS_PER_BLOCK - 1) / NPTS_PER_BLOCK;
    hashgrid_mlp_kernel<<<blocks, NPTS_PER_BLOCK, 0, stream>>>(
        coords, emb, W0, b0, W1, b1, W2, b2, out, n);
}